// Round 8
// baseline (7655.495 us; speedup 1.0000x reference)
//
#include <hip/hip_runtime.h>
#include <stdint.h>

// ================= problem constants =================
#define B_SZ   128
#define T_LEN  2048
#define DIN    256
#define NU     512
#define NOUT   64
#define EPS_F  0.01f
#define GAM_F  0.01f
#define KT     8
#define NTILES (T_LEN / KT)          // 256
#define NREG   89                    // A-frags in registers per wave
#define NLDSF  39                    // A-frags in LDS per wave (89+39 = 128 = 8nt x 16kk)

typedef uint32_t u32;
typedef _Float16 h16;
typedef _Float16 __attribute__((ext_vector_type(2))) h16x2;
typedef _Float16 __attribute__((ext_vector_type(8))) h16x8;
typedef float    __attribute__((ext_vector_type(4))) f32x4;

typedef const __attribute__((address_space(1))) u32* gas_u32p;
typedef __attribute__((address_space(3))) u32* las_u32p;

// ws layout (u32 units):
//   WS_A   : 131072 (512KB) A = W - W^T - gamma*I as MFMA B-frags [(w*8+nt)*16+kk][lane][4]
//   WS_WH  : 65536  (256KB) Vh_w as MFMA B-frags [(w*8+nt)*8+kkp][lane][4]
//   WS_WZ  : 65536  (256KB) Vz_w same layout
//   WS_PHZ : 128 chains x 8192 (4MB): proj ring [chain][parity][srow 0..7][col 0..511]
//            u32 = pack2(vh, vz) f16 pair
#define WS_A   0
#define WS_WH  131072
#define WS_WZ  196608
#define WS_PHZ 262144

__device__ __forceinline__ u32 pack2(float lo, float hi) {
  h16x2 v; v.x = (h16)lo; v.y = (h16)hi;
  return __builtin_bit_cast(u32, v);
}
__device__ __forceinline__ h16x8 as8(uint4 q) { return __builtin_bit_cast(h16x8, q); }

// ================= prep: pack A + proj weights into MFMA fragment layout =================
__global__ void antirnn_prep(const float* __restrict__ Vh_w,
                             const float* __restrict__ Vz_w,
                             const float* __restrict__ W,
                             u32* __restrict__ ws) {
  const int idx = blockIdx.x * blockDim.x + threadIdx.x;
  const int stride = gridDim.x * blockDim.x;

  // A-frags: U = (((w*8+nt)*16+kk)*64+l)*4+e
  // col j = w*128 + nt*16 + (l&15); rows k0 = kk*32 + (l>>4)*8 + 2e, k0+1
  for (int u = idx; u < 131072; u += stride) {
    int e  = u & 3;
    int l  = (u >> 2) & 63;
    int kk = (u >> 8) & 15;
    int nt = (u >> 12) & 7;
    int w  = (u >> 15) & 3;
    int j  = w * 128 + nt * 16 + (l & 15);
    int k0 = kk * 32 + (l >> 4) * 8 + 2 * e;
    int k1 = k0 + 1;
    float lo = W[k0 * NU + j] - W[j * NU + k0] - (k0 == j ? GAM_F : 0.f);
    float hi = W[k1 * NU + j] - W[j * NU + k1] - (k1 == j ? GAM_F : 0.f);
    ws[WS_A + u] = pack2(lo, hi);
  }
  // W-frags: U2 = (((w*8+nt)*8+kkp)*64+l)*4+e ; unit n, k over DIN
  for (int u = idx; u < 65536; u += stride) {
    int e   = u & 3;
    int l   = (u >> 2) & 63;
    int kkp = (u >> 8) & 7;
    int nt  = (u >> 11) & 7;
    int w   = (u >> 14) & 3;
    int n   = w * 128 + nt * 16 + (l & 15);
    int k0  = kkp * 32 + (l >> 4) * 8 + 2 * e;
    ws[WS_WH + u] = pack2(Vh_w[n * DIN + k0], Vh_w[n * DIN + k0 + 1]);
    ws[WS_WZ + u] = pack2(Vz_w[n * DIN + k0], Vz_w[n * DIN + k0 + 1]);
  }
}

// ================= scan: 128 WGs x 256 thr (4 waves, 1 wave/SIMD); one WG = one chain =================
__global__ __launch_bounds__(256, 1) void antirnn_scan(
    const float* __restrict__ x,
    const float* __restrict__ vh_b, const float* __restrict__ vz_b,
    const float* __restrict__ fc_w, const float* __restrict__ fc_b,
    u32* __restrict__ ws, float* __restrict__ out) {

  __shared__ u32 ldsA[4 * NLDSF * 256];   // 156KB: LDS A-frags [w][ls][lane*4]
  __shared__ u32 hp[2][256];              // 2KB: h as f16x2 pairs, dbuf by step parity

  const int tid = threadIdx.x;
  const int w   = tid >> 6;               // wave: cols [w*128, w*128+128)
  const int l   = tid & 63;
  const int lg  = l >> 4;
  const int ln  = l & 15;
  const int b   = blockIdx.x;

  const int c0 = w * 128 + 32 * lg + ln;  // owned cols (nt=2lg and 2lg+1)
  const int c1 = c0 + 16;

  // ---- A-frags: 89 regs (nt0..4 full, nt5 kk0..8) + 39 LDS (nt5 kk9.. , nt6, nt7) ----
  uint4 areg[NREG];
  const uint4* A4 = reinterpret_cast<const uint4*>(ws + WS_A);
#pragma unroll
  for (int nt = 0; nt < 5; ++nt)
#pragma unroll
    for (int kk = 0; kk < 16; ++kk)
      areg[nt * 16 + kk] = A4[((w * 8 + nt) * 16 + kk) * 64 + l];
#pragma unroll
  for (int kk = 0; kk < 9; ++kk)
    areg[80 + kk] = A4[((w * 8 + 5) * 16 + kk) * 64 + l];
#pragma unroll
  for (int ls = 0; ls < NLDSF; ++ls) {
    const int nt = (ls < 7) ? 5 : (ls < 23) ? 6 : 7;
    const int kk = (ls < 7) ? (ls + 9) : (ls < 23) ? (ls - 7) : (ls - 23);
    const u32* src = ws + WS_A + (((w * 8 + nt) * 16 + kk) * 64 + l) * 4;
    __builtin_amdgcn_global_load_lds((gas_u32p)src,
                                     (las_u32p)&ldsA[(w * NLDSF + ls) * 256], 16, 0, 0);
  }

  hp[0][tid] = 0; hp[1][tid] = 0;
  const float bh0 = vh_b[c0], bz0 = vz_b[c0];
  const float bh1 = vh_b[c1], bz1 = vz_b[c1];
  float hv0 = 0.f, hv1 = 0.f;

  const uint4* WH4 = reinterpret_cast<const uint4*>(ws + WS_WH);
  const uint4* WZ4 = reinterpret_cast<const uint4*>(ws + WS_WZ);
  const float* xb  = x + (long)b * T_LEN * DIN;
  u32* wphz = ws + WS_PHZ + b * 8192;

  asm volatile("s_waitcnt vmcnt(0)" ::: "memory");
  __syncthreads();

  // ---- prologue: proj tile 0 -> parity 0 ----
#pragma unroll 1
  for (int pb = 0; pb < 4; ++pb) {
    const int ntA = 2 * pb, ntB = ntA + 1;
    const uint4* bHA = WH4 + ((w * 8 + ntA) * 8) * 64 + l;
    const uint4* bHB = WH4 + ((w * 8 + ntB) * 8) * 64 + l;
    const uint4* bZA = WZ4 + ((w * 8 + ntA) * 8) * 64 + l;
    const uint4* bZB = WZ4 + ((w * 8 + ntB) * 8) * 64 + l;
    const float* xrow = xb + (long)(ln & 7) * DIN;
    f32x4 pA = {0.f,0.f,0.f,0.f}, pB = pA, qA = pA, qB = pA;
#pragma unroll 1
    for (int kkp = 0; kkp < 8; ++kkp) {
      float4 xv0 = *reinterpret_cast<const float4*>(xrow + kkp * 32 + lg * 8);
      float4 xv1 = *reinterpret_cast<const float4*>(xrow + kkp * 32 + lg * 8 + 4);
      h16x8 xf;
      xf[0]=(h16)xv0.x; xf[1]=(h16)xv0.y; xf[2]=(h16)xv0.z; xf[3]=(h16)xv0.w;
      xf[4]=(h16)xv1.x; xf[5]=(h16)xv1.y; xf[6]=(h16)xv1.z; xf[7]=(h16)xv1.w;
      pA = __builtin_amdgcn_mfma_f32_16x16x32_f16(xf, as8(bHA[kkp*64]), pA, 0,0,0);
      pB = __builtin_amdgcn_mfma_f32_16x16x32_f16(xf, as8(bHB[kkp*64]), pB, 0,0,0);
      qA = __builtin_amdgcn_mfma_f32_16x16x32_f16(xf, as8(bZA[kkp*64]), qA, 0,0,0);
      qB = __builtin_amdgcn_mfma_f32_16x16x32_f16(xf, as8(bZB[kkp*64]), qB, 0,0,0);
    }
    if (lg < 2) {
#pragma unroll
      for (int r = 0; r < 4; ++r) {
        int srow = 4 * lg + r;
        wphz[srow * 512 + (w * 128 + ntA * 16 + ln)] = pack2(pA[r], qA[r]);
        wphz[srow * 512 + (w * 128 + ntB * 16 + ln)] = pack2(pB[r], qB[r]);
      }
    }
  }
  __syncthreads();

  // ---- main loop: 256 tiles x 8 steps ----
#pragma unroll 1
  for (int tile = 0; tile < NTILES; ++tile) {
    const int tsrc = (tile + 1 < NTILES) ? (tile + 1) : (NTILES - 1);
    const float* xrow = xb + (long)(tsrc * KT + (ln & 7)) * DIN;
    const int consBase = (tile & 1) * 4096;
    const int prodBase = ((tile + 1) & 1) * 4096;
    f32x4 pA = {0.f,0.f,0.f,0.f}, pB = pA, qA = pA, qB = pA;

#pragma unroll 1
    for (int sp = 0; sp < KT; ++sp) {
      const int pb  = sp >> 1;
      const int phs = sp & 1;
      const int ntA = 2 * pb, ntB = ntA + 1;

      // --- consume vh/vz for this step (volatile -> L1-bypass; latency hidden by rec) ---
      u32 pv0 = *(const volatile u32*)(wphz + consBase + sp * 512 + c0);
      u32 pv1 = *(const volatile u32*)(wphz + consBase + sp * 512 + c1);

      // --- issue x loads for this step's proj quarter (land during rec) ---
      float4 xa[4], xc[4];
#pragma unroll
      for (int kq = 0; kq < 4; ++kq) {
        const int kkp = phs * 4 + kq;
        xa[kq] = *reinterpret_cast<const float4*>(xrow + kkp * 32 + lg * 8);
        xc[kq] = *reinterpret_cast<const float4*>(xrow + kkp * 32 + lg * 8 + 4);
      }

      // --- recurrence: u = h @ A, 128 MFMA (8 nt x 16 kk) ---
      const u32* hpc = hp[phs];
      u32* hpn = hp[1 - phs];
      f32x4 acc[8];
#pragma unroll
      for (int nt = 0; nt < 8; ++nt) acc[nt] = (f32x4){0.f,0.f,0.f,0.f};
#pragma unroll
      for (int kk = 0; kk < 16; ++kk) {
        h16x8 hf = *reinterpret_cast<const h16x8*>(hpc + kk * 16 + lg * 4);
#pragma unroll
        for (int nt = 0; nt < 8; ++nt) {
          h16x8 bf;
          if (nt < 5)                 bf = as8(areg[nt * 16 + kk]);
          else if (nt == 5 && kk < 9) bf = as8(areg[80 + kk]);
          else {
            const int ls = (nt == 5) ? (kk - 9) : (nt == 6) ? (7 + kk) : (23 + kk);
            bf = *reinterpret_cast<const h16x8*>(&ldsA[(w * NLDSF + ls) * 256 + l * 4]);
          }
          acc[nt] = __builtin_amdgcn_mfma_f32_16x16x32_f16(hf, bf, acc[nt], 0, 0, 0);
        }
      }

      // --- proj quarter for tile+1 (4 kkp x 4 MFMA) ---
      {
        const uint4* bHA = WH4 + ((w * 8 + ntA) * 8) * 64 + l;
        const uint4* bHB = WH4 + ((w * 8 + ntB) * 8) * 64 + l;
        const uint4* bZA = WZ4 + ((w * 8 + ntA) * 8) * 64 + l;
        const uint4* bZB = WZ4 + ((w * 8 + ntB) * 8) * 64 + l;
        if (phs == 0) { pA = (f32x4){0.f,0.f,0.f,0.f}; pB = pA; qA = pA; qB = pA; }
#pragma unroll
        for (int kq = 0; kq < 4; ++kq) {
          const int kkp = phs * 4 + kq;
          h16x8 xf;
          xf[0]=(h16)xa[kq].x; xf[1]=(h16)xa[kq].y; xf[2]=(h16)xa[kq].z; xf[3]=(h16)xa[kq].w;
          xf[4]=(h16)xc[kq].x; xf[5]=(h16)xc[kq].y; xf[6]=(h16)xc[kq].z; xf[7]=(h16)xc[kq].w;
          pA = __builtin_amdgcn_mfma_f32_16x16x32_f16(xf, as8(bHA[kkp*64]), pA, 0,0,0);
          pB = __builtin_amdgcn_mfma_f32_16x16x32_f16(xf, as8(bHB[kkp*64]), pB, 0,0,0);
          qA = __builtin_amdgcn_mfma_f32_16x16x32_f16(xf, as8(bZA[kkp*64]), qA, 0,0,0);
          qB = __builtin_amdgcn_mfma_f32_16x16x32_f16(xf, as8(bZB[kkp*64]), qB, 0,0,0);
        }
        if (phs == 1 && lg < 2) {
#pragma unroll
          for (int r = 0; r < 4; ++r) {
            int srow = 4 * lg + r;
            wphz[prodBase + srow * 512 + (w * 128 + ntA * 16 + ln)] = pack2(pA[r], qA[r]);
            wphz[prodBase + srow * 512 + (w * 128 + ntB * 16 + ln)] = pack2(pB[r], qB[r]);
          }
        }
      }

      // --- epilogue: all D rows equal -> own cols' u = acc[2lg].x / acc[2lg+1].x ---
      {
        float u0 = (lg == 0) ? acc[0].x : (lg == 1) ? acc[2].x : (lg == 2) ? acc[4].x : acc[6].x;
        float u1 = (lg == 0) ? acc[1].x : (lg == 1) ? acc[3].x : (lg == 2) ? acc[5].x : acc[7].x;
        h16x2 q0 = __builtin_bit_cast(h16x2, pv0);
        h16x2 q1 = __builtin_bit_cast(h16x2, pv1);
        float uh0 = u0 + (float)q0.x + bh0, uz0 = u0 + (float)q0.y + bz0;
        float uh1 = u1 + (float)q1.x + bh1, uz1 = u1 + (float)q1.y + bz1;
        float c0h = fminf(fmaxf(uh0, -20.f), 20.f);
        float c1h = fminf(fmaxf(uh1, -20.f), 20.f);
        float e0 = __expf(2.f * c0h), e1 = __expf(2.f * c1h);
        float th0 = 1.f - 2.f / (e0 + 1.f), th1 = 1.f - 2.f / (e1 + 1.f);
        float sg0 = 1.f / (1.f + __expf(-uz0)), sg1 = 1.f / (1.f + __expf(-uz1));
        hv0 += EPS_F * th0 * sg0;
        hv1 += EPS_F * th1 * sg1;
        float o0 = __shfl_xor(hv0, 1, 64);
        float o1 = __shfl_xor(hv1, 1, 64);
        if (!(ln & 1)) {
          hpn[w * 64 + 16 * lg + (ln >> 1)]     = pack2(hv0, o0);
          hpn[w * 64 + 16 * lg + 8 + (ln >> 1)] = pack2(hv1, o1);
        }
      }
      __syncthreads();
    }
  }

  // ---- final fc: out[b][o] = fc_b[o] + sum_c h[c]*fc_w[o][c] (reuse ldsA as f32 h buffer) ----
  float* hbuf = reinterpret_cast<float*>(ldsA);
  hbuf[c0] = hv0;
  hbuf[c1] = hv1;
  __syncthreads();
  if (tid < NOUT) {
    float acc = fc_b[tid];
    const float* fr = fc_w + tid * NU;
#pragma unroll 4
    for (int c = 0; c < NU; ++c) acc += hbuf[c] * fr[c];
    out[b * NOUT + tid] = acc;
  }
}

// ================= launcher =================
extern "C" void kernel_launch(void* const* d_in, const int* in_sizes, int n_in,
                              void* d_out, int out_size, void* d_ws, size_t ws_size,
                              hipStream_t stream) {
  const float* x    = (const float*)d_in[0];
  const float* Vh_w = (const float*)d_in[1];
  const float* Vh_b = (const float*)d_in[2];
  const float* Vz_w = (const float*)d_in[3];
  const float* Vz_b = (const float*)d_in[4];
  const float* W    = (const float*)d_in[5];
  const float* fc_w = (const float*)d_in[6];
  const float* fc_b = (const float*)d_in[7];
  float* out = (float*)d_out;
  u32*   ws  = (u32*)d_ws;

  antirnn_prep<<<512, 256, 0, stream>>>(Vh_w, Vz_w, W, ws);
  antirnn_scan<<<128, 256, 0, stream>>>(x, Vh_b, Vz_b, fc_w, fc_b, ws, out);
}